// Round 1
// baseline (2882.859 us; speedup 1.0000x reference)
//
#include <hip/hip_runtime.h>

typedef __bf16 bf16_t;
typedef __attribute__((ext_vector_type(8))) __bf16 bf16x8;
typedef __attribute__((ext_vector_type(4))) float f32x4;

#define NSEQ 1024
#define SLEN 100
#define HID  512

__device__ __forceinline__ float sigf(float x) { return 1.0f / (1.0f + __expf(-x)); }
__device__ __forceinline__ float tanh_(float x) { return 1.0f - 2.0f / (__expf(2.0f * x) + 1.0f); }

__device__ __forceinline__ bf16x8 cvt8(float4 a, float4 b) {
    bf16x8 v;
    v[0] = (__bf16)a.x; v[1] = (__bf16)a.y; v[2] = (__bf16)a.z; v[3] = (__bf16)a.w;
    v[4] = (__bf16)b.x; v[5] = (__bf16)b.y; v[6] = (__bf16)b.z; v[7] = (__bf16)b.w;
    return v;
}

// ---------------------------------------------------------------------------
// Embedding GEMM: emb[t][seq][h] = sum_d x[seq][t][d] * W_e[h][d] + b_e[h]
// rows r = t*1024+seq (so each timestep slice is contiguous for the LSTM).
// Block: 64 rows x 256 cols, K=64. 4 waves, wave = 16 rows x 256 cols.
// ---------------------------------------------------------------------------
__global__ __launch_bounds__(256)
void embed_kernel(const float* __restrict__ x, const float* __restrict__ We,
                  const float* __restrict__ be, bf16_t* __restrict__ emb)
{
    __shared__ bf16_t bsm[8 * 256 * 8];   // [q=k/8][col][8] bf16 = 32 KB
    const int bid = blockIdx.x;
    const int rowblk = bid >> 1;
    const int col0 = (bid & 1) << 8;
    const int tid = threadIdx.x;

    // stage W_e^T slice (B operand): bsm[q][col][e] = We[col0+col][q*8+e]
    {
        const int col = tid;  // 0..255
        const float* src = We + (size_t)(col0 + col) * 64;
        #pragma unroll
        for (int q = 0; q < 8; ++q) {
            float4 f0 = *(const float4*)(src + q * 8);
            float4 f1 = *(const float4*)(src + q * 8 + 4);
            *(bf16x8*)&bsm[(q * 256 + col) * 8] = cvt8(f0, f1);
        }
    }
    __syncthreads();

    const int l = tid & 63, w = tid >> 6;
    const int lo = l & 15, hi = l >> 4;
    const int rowbase = rowblk * 64 + w * 16;
    const int row_a = rowbase + lo;              // A-frag row
    const int seq = row_a & (NSEQ - 1);
    const int t = row_a >> 10;
    const float* xrow = x + ((size_t)seq * SLEN + t) * 64;

    bf16x8 a0, a1;
    {
        const float* p = xrow + hi * 8;
        a0 = cvt8(*(const float4*)p, *(const float4*)(p + 4));
        p = xrow + 32 + hi * 8;
        a1 = cvt8(*(const float4*)p, *(const float4*)(p + 4));
    }

    #pragma unroll
    for (int nf = 0; nf < 16; ++nf) {
        f32x4 acc = {0.f, 0.f, 0.f, 0.f};
        bf16x8 b0 = *(const bf16x8*)&bsm[((0 * 4 + hi) * 256 + nf * 16 + lo) * 8];
        bf16x8 b1 = *(const bf16x8*)&bsm[((1 * 4 + hi) * 256 + nf * 16 + lo) * 8];
        acc = __builtin_amdgcn_mfma_f32_16x16x32_bf16(a0, b0, acc, 0, 0, 0);
        acc = __builtin_amdgcn_mfma_f32_16x16x32_bf16(a1, b1, acc, 0, 0, 0);
        const int col = col0 + nf * 16 + lo;
        const float bias = be[col];
        #pragma unroll
        for (int r = 0; r < 4; ++r) {
            const int rr = rowbase + hi * 4 + r;  // C/D row = (lane>>4)*4 + reg
            emb[(size_t)rr * HID + col] = (bf16_t)(acc[r] + bias);
        }
    }
}

// ---------------------------------------------------------------------------
// Persistent masked-LSTM kernel.
// Grid = 256 blocks: m = bid>>5 (M-tile of 128 seqs), jsl = bid&31 (16 hidden
// units -> 64 gate columns = 4 frags {i,f,g,o}). Weights slice (64x1024 bf16 =
// 128 KB) stays in LDS for all 100 steps. c-state lives in registers.
// Per-step sync: per-group (32 blocks) monotonic atomic counter barrier.
// ---------------------------------------------------------------------------
__global__ __launch_bounds__(512)
void lstm_kernel(const bf16_t* __restrict__ emb, const int* __restrict__ mask,
                 const float* __restrict__ Wih, const float* __restrict__ Whh,
                 const float* __restrict__ bih, const float* __restrict__ bhh,
                 const float* __restrict__ h0, const float* __restrict__ c0,
                 bf16_t* __restrict__ hbuf,        // [2][1024][512] bf16
                 unsigned int* __restrict__ cnt,   // 8 counters, stride 64 uints
                 float* __restrict__ out)
{
    extern __shared__ bf16_t wsm[];   // [q=k/8 (128)][col (64)][8] = 128 KB
    const int bid = blockIdx.x;
    const int m = bid >> 5;           // 0..7
    const int jsl = bid & 31;         // 0..31
    const int jbase = jsl * 16;
    const int tid = threadIdx.x;

    // ---- stage weight slice: wsm[q][col][e] = Wcat[G(col)][q*8+e] ----
    // col = grp*16 + jj ; G = grp*512 + jbase + jj ; k<512 -> W_ih else W_hh
    {
        const int col = tid & 63;
        const int qg = tid >> 6;          // 0..7
        const int grp = col >> 4;
        const int jj = col & 15;
        const int G = grp * 512 + jbase + jj;
        #pragma unroll
        for (int i = 0; i < 16; ++i) {
            const int q = qg * 16 + i;    // 0..127
            const int k0 = q * 8;
            const float* src = (k0 < 512) ? (Wih + (size_t)G * 512 + k0)
                                          : (Whh + (size_t)G * 512 + (k0 - 512));
            float4 f0 = *(const float4*)src;
            float4 f1 = *(const float4*)(src + 4);
            *(bf16x8*)&wsm[(q * 64 + col) * 8] = cvt8(f0, f1);
        }
    }

    const int l = tid & 63, w = tid >> 6;
    const int lo = l & 15, hi = l >> 4;
    const int seqbase = m * 128 + w * 16;
    const int jg = jbase + lo;            // this lane's hidden unit

    // per-gate biases for this lane's hidden unit
    float bs[4];
    #pragma unroll
    for (int g = 0; g < 4; ++g) bs[g] = bih[g * 512 + jg] + bhh[g * 512 + jg];

    // init c and h(0) = mask0 ? emb0 : h0
    float c_reg[4];
    const float c0v = c0[jg], h0v = h0[jg];
    #pragma unroll
    for (int r = 0; r < 4; ++r) {
        const int seq = seqbase + hi * 4 + r;
        c_reg[r] = c0v;
        const int mb = mask[(size_t)seq * SLEN + 0];
        const float e0 = (float)emb[(size_t)seq * HID + jg];  // t=0 slice
        const float hv = mb ? e0 : h0v;
        hbuf[(size_t)seq * HID + jg] = (bf16_t)hv;            // buffer 0
    }
    __syncthreads();
    if (tid == 0) {
        __threadfence();
        atomicAdd(&cnt[m * 64], 1u);
    }

    const int koff = hi * 8;

    for (int t = 0; t < SLEN; ++t) {
        // ---- group barrier: wait for all 32 blocks of group m ----
        if (tid == 0) {
            const unsigned target = 32u * (unsigned)(t + 1);
            unsigned it = 0;
            while (__hip_atomic_load(&cnt[m * 64], __ATOMIC_ACQUIRE,
                                     __HIP_MEMORY_SCOPE_AGENT) < target &&
                   ++it < (1u << 26)) {
                __builtin_amdgcn_s_sleep(1);
            }
            __threadfence();
        }
        __syncthreads();

        const bf16_t* hb_r = hbuf + (size_t)(t & 1) * (NSEQ * HID);
        bf16_t* hb_w = hbuf + (size_t)((t + 1) & 1) * (NSEQ * HID);

        // A-frag row for this lane: seq_a = seqbase + lo
        const int seq_a = seqbase + lo;
        const bf16_t* hrow = hb_r + (size_t)seq_a * HID;
        const int mb = mask[(size_t)seq_a * SLEN + t];
        const bf16_t* xrow = mb ? (emb + ((size_t)t * NSEQ + seq_a) * HID) : hrow;

        f32x4 acc[4];
        #pragma unroll
        for (int nf = 0; nf < 4; ++nf) acc[nf] = (f32x4){0.f, 0.f, 0.f, 0.f};

        // K = [0,512): xt = select(mask, emb, h)
        #pragma unroll
        for (int kt = 0; kt < 16; ++kt) {
            const bf16x8 a = *(const bf16x8*)(xrow + kt * 32 + koff);
            #pragma unroll
            for (int nf = 0; nf < 4; ++nf) {
                const bf16x8 b =
                    *(const bf16x8*)&wsm[((kt * 4 + hi) * 64 + nf * 16 + lo) * 8];
                acc[nf] = __builtin_amdgcn_mfma_f32_16x16x32_bf16(a, b, acc[nf], 0, 0, 0);
            }
        }
        // K = [512,1024): h
        #pragma unroll
        for (int kt = 0; kt < 16; ++kt) {
            const bf16x8 a = *(const bf16x8*)(hrow + kt * 32 + koff);
            #pragma unroll
            for (int nf = 0; nf < 4; ++nf) {
                const bf16x8 b =
                    *(const bf16x8*)&wsm[(((kt + 16) * 4 + hi) * 64 + nf * 16 + lo) * 8];
                acc[nf] = __builtin_amdgcn_mfma_f32_16x16x32_bf16(a, b, acc[nf], 0, 0, 0);
            }
        }

        // ---- lane-local LSTM cell update (acc[0..3] = i,f,g,o at unit jg) ----
        #pragma unroll
        for (int r = 0; r < 4; ++r) {
            const float iv = acc[0][r] + bs[0];
            const float fv = acc[1][r] + bs[1];
            const float gv = acc[2][r] + bs[2];
            const float ov = acc[3][r] + bs[3];
            const float cn = sigf(fv) * c_reg[r] + sigf(iv) * tanh_(gv);
            c_reg[r] = cn;
            const float hv = sigf(ov) * tanh_(cn);
            const int seq = seqbase + hi * 4 + r;
            hb_w[(size_t)seq * HID + jg] = (bf16_t)hv;
            if (t == SLEN - 1) out[(size_t)seq * HID + jg] = hv;
        }
        __syncthreads();
        if (tid == 0) {
            __threadfence();
            atomicAdd(&cnt[m * 64], 1u);
        }
    }
}

// ---------------------------------------------------------------------------
extern "C" void kernel_launch(void* const* d_in, const int* in_sizes, int n_in,
                              void* d_out, int out_size, void* d_ws, size_t ws_size,
                              hipStream_t stream)
{
    const float* x    = (const float*)d_in[0];
    const int*   mask = (const int*)d_in[1];
    const float* We   = (const float*)d_in[2];
    const float* be   = (const float*)d_in[3];
    const float* Wih  = (const float*)d_in[4];
    const float* Whh  = (const float*)d_in[5];
    const float* bih  = (const float*)d_in[6];
    const float* bhh  = (const float*)d_in[7];
    const float* h0   = (const float*)d_in[8];
    const float* c0   = (const float*)d_in[9];
    float* out = (float*)d_out;

    unsigned char* ws = (unsigned char*)d_ws;
    unsigned int* cnt = (unsigned int*)ws;                       // 4 KB
    bf16_t* hbuf = (bf16_t*)(ws + 4096);                         // 2 MB
    bf16_t* emb  = (bf16_t*)(ws + 4096 + (size_t)2 * NSEQ * HID * 2);  // ~100 MB

    hipMemsetAsync(cnt, 0, 4096, stream);

    embed_kernel<<<3200, 256, 0, stream>>>(x, We, be, emb);

    hipFuncSetAttribute(reinterpret_cast<const void*>(lstm_kernel),
                        hipFuncAttributeMaxDynamicSharedMemorySize, 131072);
    lstm_kernel<<<256, 512, 131072, stream>>>(emb, mask, Wih, Whh, bih, bhh,
                                              h0, c0, hbuf, cnt, out);
}

// Round 2
// 1556.098 us; speedup vs baseline: 1.8526x; 1.8526x over previous
//
#include <hip/hip_runtime.h>

typedef __bf16 bf16_t;
typedef __attribute__((ext_vector_type(8))) __bf16 bf16x8;
typedef __attribute__((ext_vector_type(4))) float f32x4;

#define NSEQ 1024
#define SLEN 100
#define HID  512

__device__ __forceinline__ float sigf(float x) { return 1.0f / (1.0f + __expf(-x)); }
__device__ __forceinline__ float tanh_(float x) { return 1.0f - 2.0f / (__expf(2.0f * x) + 1.0f); }

__device__ __forceinline__ bf16x8 cvt8(float4 a, float4 b) {
    bf16x8 v;
    v[0] = (__bf16)a.x; v[1] = (__bf16)a.y; v[2] = (__bf16)a.z; v[3] = (__bf16)a.w;
    v[4] = (__bf16)b.x; v[5] = (__bf16)b.y; v[6] = (__bf16)b.z; v[7] = (__bf16)b.w;
    return v;
}

// ---------------------------------------------------------------------------
// Embedding GEMM: emb[t][seq][h] = sum_d x[seq][t][d] * W_e[h][d] + b_e[h]
// ---------------------------------------------------------------------------
__global__ __launch_bounds__(256)
void embed_kernel(const float* __restrict__ x, const float* __restrict__ We,
                  const float* __restrict__ be, bf16_t* __restrict__ emb)
{
    __shared__ bf16_t bsm[8 * 256 * 8];   // [q=k/8][col][8] bf16 = 32 KB
    const int bid = blockIdx.x;
    const int rowblk = bid >> 1;
    const int col0 = (bid & 1) << 8;
    const int tid = threadIdx.x;

    {
        const int col = tid;  // 0..255
        const float* src = We + (size_t)(col0 + col) * 64;
        #pragma unroll
        for (int q = 0; q < 8; ++q) {
            float4 f0 = *(const float4*)(src + q * 8);
            float4 f1 = *(const float4*)(src + q * 8 + 4);
            *(bf16x8*)&bsm[(q * 256 + col) * 8] = cvt8(f0, f1);
        }
    }
    __syncthreads();

    const int l = tid & 63, w = tid >> 6;
    const int lo = l & 15, hi = l >> 4;
    const int rowbase = rowblk * 64 + w * 16;
    const int row_a = rowbase + lo;
    const int seq = row_a & (NSEQ - 1);
    const int t = row_a >> 10;
    const float* xrow = x + ((size_t)seq * SLEN + t) * 64;

    bf16x8 a0, a1;
    {
        const float* p = xrow + hi * 8;
        a0 = cvt8(*(const float4*)p, *(const float4*)(p + 4));
        p = xrow + 32 + hi * 8;
        a1 = cvt8(*(const float4*)p, *(const float4*)(p + 4));
    }

    #pragma unroll
    for (int nf = 0; nf < 16; ++nf) {
        f32x4 acc = {0.f, 0.f, 0.f, 0.f};
        bf16x8 b0 = *(const bf16x8*)&bsm[((0 * 4 + hi) * 256 + nf * 16 + lo) * 8];
        bf16x8 b1 = *(const bf16x8*)&bsm[((1 * 4 + hi) * 256 + nf * 16 + lo) * 8];
        acc = __builtin_amdgcn_mfma_f32_16x16x32_bf16(a0, b0, acc, 0, 0, 0);
        acc = __builtin_amdgcn_mfma_f32_16x16x32_bf16(a1, b1, acc, 0, 0, 0);
        const int col = col0 + nf * 16 + lo;
        const float bias = be[col];
        #pragma unroll
        for (int r = 0; r < 4; ++r) {
            const int rr = rowbase + hi * 4 + r;
            emb[(size_t)rr * HID + col] = (bf16_t)(acc[r] + bias);
        }
    }
}

// ---------------------------------------------------------------------------
// Persistent masked-LSTM kernel.
// m = bid&7 (XCD-local group of 32 blocks, 128 seqs), jsl = bid>>3 (16 hidden
// units -> 64 gate cols {i,f,g,o}). Weight slice 128 KB LDS for all 100 steps.
// Barrier: relaxed spin + single acquire; release fetch_add.
// ---------------------------------------------------------------------------
__global__ __launch_bounds__(512, 2)
void lstm_kernel(const bf16_t* __restrict__ emb, const int* __restrict__ mask,
                 const float* __restrict__ Wih, const float* __restrict__ Whh,
                 const float* __restrict__ bih, const float* __restrict__ bhh,
                 const float* __restrict__ h0, const float* __restrict__ c0,
                 bf16_t* __restrict__ hbuf,        // [2][1024][512] bf16
                 unsigned int* __restrict__ cnt,   // 8 counters, stride 64 uints
                 float* __restrict__ out)
{
    extern __shared__ bf16_t wsm[];   // [q=k/8 (128)][col (64)][8] = 128 KB
    const int bid = blockIdx.x;
    const int m = bid & 7;            // group (XCD-local with round-robin dispatch)
    const int jsl = bid >> 3;         // 0..31
    const int jbase = jsl * 16;
    const int tid = threadIdx.x;

    // ---- stage weight slice: wsm[q][col][e] = Wcat[G(col)][q*8+e] ----
    {
        const int col = tid & 63;
        const int qg = tid >> 6;          // 0..7
        const int grp = col >> 4;
        const int jj = col & 15;
        const int G = grp * 512 + jbase + jj;
        #pragma unroll
        for (int i = 0; i < 16; ++i) {
            const int q = qg * 16 + i;    // 0..127
            const int k0 = q * 8;
            const float* src = (k0 < 512) ? (Wih + (size_t)G * 512 + k0)
                                          : (Whh + (size_t)G * 512 + (k0 - 512));
            float4 f0 = *(const float4*)src;
            float4 f1 = *(const float4*)(src + 4);
            *(bf16x8*)&wsm[(q * 64 + col) * 8] = cvt8(f0, f1);
        }
    }

    const int l = tid & 63, w = tid >> 6;
    const int lo = l & 15, hi = l >> 4;
    const int seqbase = m * 128 + w * 16;
    const int jg = jbase + lo;

    float bs[4];
    #pragma unroll
    for (int g = 0; g < 4; ++g) bs[g] = bih[g * 512 + jg] + bhh[g * 512 + jg];

    // init c and h(0) = mask0 ? emb0 : h0
    float c_reg[4];
    const float c0v = c0[jg], h0v = h0[jg];
    #pragma unroll
    for (int r = 0; r < 4; ++r) {
        const int seq = seqbase + hi * 4 + r;
        c_reg[r] = c0v;
        const int mb0 = mask[(size_t)seq * SLEN + 0];
        const float e0 = (float)emb[(size_t)seq * HID + jg];
        hbuf[(size_t)seq * HID + jg] = (bf16_t)(mb0 ? e0 : h0v);
    }
    __syncthreads();
    if (tid == 0)
        __hip_atomic_fetch_add(&cnt[m * 64], 1u, __ATOMIC_RELEASE,
                               __HIP_MEMORY_SCOPE_AGENT);

    const int koff = hi * 8;
    const int seq_a = seqbase + lo;       // this lane's A row

    for (int t = 0; t < SLEN; ++t) {
        // ---- prefetch (independent of h(t)) BEFORE the barrier ----
        const int mb = mask[(size_t)seq_a * SLEN + t];
        const bf16_t* erow = emb + ((size_t)t * NSEQ + seq_a) * HID;
        bf16x8 ex[16];
        #pragma unroll
        for (int kt = 0; kt < 16; ++kt)
            ex[kt] = *(const bf16x8*)(erow + kt * 32 + koff);

        // ---- group barrier: relaxed spin, one acquire ----
        if (tid == 0) {
            const unsigned target = 32u * (unsigned)(t + 1);
            unsigned it = 0;
            while (__hip_atomic_load(&cnt[m * 64], __ATOMIC_RELAXED,
                                     __HIP_MEMORY_SCOPE_AGENT) < target &&
                   ++it < (1u << 27)) {
                __builtin_amdgcn_s_sleep(1);
            }
            (void)__hip_atomic_load(&cnt[m * 64], __ATOMIC_ACQUIRE,
                                    __HIP_MEMORY_SCOPE_AGENT);
        }
        __syncthreads();

        const bf16_t* hb_r = hbuf + (size_t)(t & 1) * (NSEQ * HID);
        bf16_t* hb_w = hbuf + (size_t)((t + 1) & 1) * (NSEQ * HID);

        // ---- load h fragments once (used by both K-halves) ----
        const bf16_t* hrow = hb_r + (size_t)seq_a * HID;
        bf16x8 hf[16];
        #pragma unroll
        for (int kt = 0; kt < 16; ++kt)
            hf[kt] = *(const bf16x8*)(hrow + kt * 32 + koff);

        f32x4 acc[4];
        #pragma unroll
        for (int nf = 0; nf < 4; ++nf) acc[nf] = (f32x4){0.f, 0.f, 0.f, 0.f};

        // K = [0,512): xt = select(mask, emb, h)  -- select in registers
        #pragma unroll
        for (int kt = 0; kt < 16; ++kt) {
            const bf16x8 ax = mb ? ex[kt] : hf[kt];
            #pragma unroll
            for (int nf = 0; nf < 4; ++nf) {
                const bf16x8 b =
                    *(const bf16x8*)&wsm[((kt * 4 + hi) * 64 + nf * 16 + lo) * 8];
                acc[nf] = __builtin_amdgcn_mfma_f32_16x16x32_bf16(ax, b, acc[nf], 0, 0, 0);
            }
        }
        // K = [512,1024): h
        #pragma unroll
        for (int kt = 0; kt < 16; ++kt) {
            #pragma unroll
            for (int nf = 0; nf < 4; ++nf) {
                const bf16x8 b =
                    *(const bf16x8*)&wsm[(((kt + 16) * 4 + hi) * 64 + nf * 16 + lo) * 8];
                acc[nf] = __builtin_amdgcn_mfma_f32_16x16x32_bf16(hf[kt], b, acc[nf], 0, 0, 0);
            }
        }

        // ---- lane-local LSTM cell update ----
        #pragma unroll
        for (int r = 0; r < 4; ++r) {
            const float iv = acc[0][r] + bs[0];
            const float fv = acc[1][r] + bs[1];
            const float gv = acc[2][r] + bs[2];
            const float ov = acc[3][r] + bs[3];
            const float cn = sigf(fv) * c_reg[r] + sigf(iv) * tanh_(gv);
            c_reg[r] = cn;
            const float hv = sigf(ov) * tanh_(cn);
            const int seq = seqbase + hi * 4 + r;
            hb_w[(size_t)seq * HID + jg] = (bf16_t)hv;
            if (t == SLEN - 1) out[(size_t)seq * HID + jg] = hv;
        }
        __syncthreads();
        if (tid == 0)
            __hip_atomic_fetch_add(&cnt[m * 64], 1u, __ATOMIC_RELEASE,
                                   __HIP_MEMORY_SCOPE_AGENT);
    }
}

// ---------------------------------------------------------------------------
extern "C" void kernel_launch(void* const* d_in, const int* in_sizes, int n_in,
                              void* d_out, int out_size, void* d_ws, size_t ws_size,
                              hipStream_t stream)
{
    const float* x    = (const float*)d_in[0];
    const int*   mask = (const int*)d_in[1];
    const float* We   = (const float*)d_in[2];
    const float* be   = (const float*)d_in[3];
    const float* Wih  = (const float*)d_in[4];
    const float* Whh  = (const float*)d_in[5];
    const float* bih  = (const float*)d_in[6];
    const float* bhh  = (const float*)d_in[7];
    const float* h0   = (const float*)d_in[8];
    const float* c0   = (const float*)d_in[9];
    float* out = (float*)d_out;

    unsigned char* ws = (unsigned char*)d_ws;
    unsigned int* cnt = (unsigned int*)ws;                       // 4 KB
    bf16_t* hbuf = (bf16_t*)(ws + 4096);                         // 2 MB
    bf16_t* emb  = (bf16_t*)(ws + 4096 + (size_t)2 * NSEQ * HID * 2);  // ~100 MB

    hipMemsetAsync(cnt, 0, 4096, stream);

    embed_kernel<<<3200, 256, 0, stream>>>(x, We, be, emb);

    hipFuncSetAttribute(reinterpret_cast<const void*>(lstm_kernel),
                        hipFuncAttributeMaxDynamicSharedMemorySize, 131072);
    lstm_kernel<<<256, 512, 131072, stream>>>(emb, mask, Wih, Whh, bih, bhh,
                                              h0, c0, hbuf, cnt, out);
}